// Round 5
// baseline (3114.422 us; speedup 1.0000x reference)
//
#include <hip/hip_runtime.h>
#include <hip/hip_bf16.h>

// Problem constants (fixed by the reference)
#define N_ 100000
#define MPAD 100096          // 782 * 128
#define E_ 400000
#define B_ 2048
#define H_ 300
#define KP_ 320              // H padded to mult of 32
#define L_ 5
#define EF_ 16
#define T_ 128
#define CN_ 25000            // nodes per agg chunk (4 chunks)
#define EGB_ 813             // eproj GEMM row-blocks per chunk (813*128 = 104064 rows)
#define BNS 0.9999950000374997f  // 1/sqrt(1+1e-5)

typedef unsigned short ushort_t;
typedef short bf16x8 __attribute__((ext_vector_type(8)));
typedef float f32x4 __attribute__((ext_vector_type(4)));

__device__ __forceinline__ ushort_t f2b(float v) {
    unsigned u = __float_as_uint(v);
    unsigned r = (u + 0x7FFFu + ((u >> 16) & 1u)) >> 16;
    return (ushort_t)r;
}

__device__ __forceinline__ float b2f(ushort_t u) {
    return __uint_as_float(((unsigned)u) << 16);
}

__device__ __forceinline__ void gl_lds16(const void* g, void* l) {
    __builtin_amdgcn_global_load_lds(
        (const __attribute__((address_space(1))) void*)g,
        (__attribute__((address_space(3))) void*)l, 16, 0, 0);
}

// swizzled column for logical (row r, col j) in a swizzled bf16 buffer
__device__ __forceinline__ int swzcol(int r, int j) {
    int u = ((j >> 3) & 3) ^ ((r >> 1) & 3);
    return (j & ~31) | (u << 3) | (j & 7);
}

// ---------------- CSR build ----------------
__global__ void k_hist(const int* __restrict__ dst, int* __restrict__ degi, int E) {
    int e = blockIdx.x * blockDim.x + threadIdx.x;
    if (e < E) atomicAdd(&degi[dst[e]], 1);
}

__global__ void k_norm(const int* __restrict__ degi, float* __restrict__ nrm,
                       float* __restrict__ invdeg, int N) {
    int n = blockIdx.x * blockDim.x + threadIdx.x;
    if (n < N) {
        float d = (float)degi[n] + 1.0f;
        nrm[n] = 1.0f / sqrtf(d);
        invdeg[n] = 1.0f / d;
    }
}

__global__ void k_scan1(const int* __restrict__ in, int* __restrict__ out,
                        int* __restrict__ partial, int N) {
    __shared__ int s[1024];
    int i = blockIdx.x * 1024 + threadIdx.x;
    int v = (i < N) ? in[i] : 0;
    s[threadIdx.x] = v;
    __syncthreads();
    for (int off = 1; off < 1024; off <<= 1) {
        int t = (threadIdx.x >= off) ? s[threadIdx.x - off] : 0;
        __syncthreads();
        s[threadIdx.x] += t;
        __syncthreads();
    }
    if (i < N) out[i] = s[threadIdx.x] - v;  // exclusive
    if (threadIdx.x == 1023) partial[blockIdx.x] = s[1023];
}

__global__ void k_scan2(int* __restrict__ partial, int nb, int* __restrict__ totalOut) {
    if (blockIdx.x == 0 && threadIdx.x == 0) {
        int run = 0;
        for (int i = 0; i < nb; i++) { int v = partial[i]; partial[i] = run; run += v; }
        *totalOut = run;
    }
}

__global__ void k_scan3(int* __restrict__ out, const int* __restrict__ partial, int N) {
    int i = blockIdx.x * 1024 + threadIdx.x;
    if (i < N) out[i] += partial[blockIdx.x];
}

// scatter edges into CSR order; pre-gather edge feats (bf16, K-pad 32) + per-edge norm
__global__ void k_scatter(const int* __restrict__ dst, const int* __restrict__ src,
                          const float* __restrict__ ef, const float* __restrict__ nrm,
                          int* __restrict__ cursor, int* __restrict__ csrc,
                          ushort_t* __restrict__ ef_bf, float* __restrict__ en_csr, int E) {
    int e = blockIdx.x * blockDim.x + threadIdx.x;
    if (e >= E) return;
    int d = dst[e], s = src[e];
    int pos = atomicAdd(&cursor[d], 1);
    csrc[pos] = s;
    en_csr[pos] = nrm[s] * nrm[d];
    const float4* ep = (const float4*)&ef[(size_t)e * EF_];
    ushort_t* op = &ef_bf[(size_t)pos * 32];
    #pragma unroll
    for (int q = 0; q < 4; q++) {
        float4 v = ep[q];
        op[q * 4 + 0] = f2b(v.x); op[q * 4 + 1] = f2b(v.y);
        op[q * 4 + 2] = f2b(v.z); op[q * 4 + 3] = f2b(v.w);
    }
}

__global__ void k_rowstart(const int* __restrict__ gid, int* __restrict__ rs, int N, int B) {
    int b = blockIdx.x * blockDim.x + threadIdx.x;
    if (b <= B) {
        int lo = 0, hi = N;
        while (lo < hi) { int mid = (lo + hi) >> 1; if (gid[mid] < b) lo = mid + 1; else hi = mid; }
        rs[b] = lo;
    }
}

// ---------------- init ----------------
__global__ void k_hinit(const int* __restrict__ nt, const float* __restrict__ emb,
                        const float* __restrict__ vn_emb,
                        ushort_t* __restrict__ h_bf) {
    int n = blockIdx.x; int j = threadIdx.x;
    if (j >= H_) return;
    float v = emb[(size_t)nt[n] * H_ + j] + vn_emb[j];
    h_bf[(size_t)n * KP_ + swzcol(n, j)] = f2b(v);
}

__global__ void k_vninit(const float* __restrict__ vn_emb, float* __restrict__ vn) {
    int b = blockIdx.x; int j = threadIdx.x;
    if (j >= H_) return;
    vn[(size_t)b * H_ + j] = vn_emb[j];
}

// weight conversion: WT[l][n][k] = W[l][k][n], bf16, zero-padded, row-swizzled
__global__ void k_convW(const float* __restrict__ W, ushort_t* __restrict__ WT,
                        int nl, int K, int Nout, int KPv, int NPBv) {
    int UPR = KPv / 8;
    int tot = nl * NPBv * UPR;
    int idx = blockIdx.x * 256 + threadIdx.x;
    if (idx >= tot) return;
    int l = idx / (NPBv * UPR); int r = idx % (NPBv * UPR);
    int n = r / UPR; int ku = r % UPR;
    int k0 = ku * 8;
    int swz = (ku & 3) ^ ((n >> 1) & 3);
    size_t d = ((size_t)l * NPBv + n) * KPv + (size_t)(k0 & ~31) + swz * 8;
    #pragma unroll
    for (int i = 0; i < 8; i++) {
        int k = k0 + i;
        float v = (k < K && n < Nout) ? W[((size_t)l * K + k) * Nout + n] : 0.f;
        WT[d + i] = f2b(v);
    }
}

// ---------------- unified bf16 MFMA GEMM ----------------
// C = epilogue(A[M,KP] @ BT[*,KP]^T + bias).  A swizzled (aswz=1) or linear (aswz=0).
// If obase: A-rows offset by *obase, M = *oend - *obase (device-side chunk size).
// Output: Cf (fp32, stride ldf) or Cb (bf16, stride ldb, swizzled iff swzout).
#define MB 128
#define NB 128
__launch_bounds__(256)
__global__ void k_bgemm(const ushort_t* __restrict__ A, const ushort_t* __restrict__ BT,
                        int M, int Nn, int KP,
                        const int* __restrict__ obase, const int* __restrict__ oend,
                        int aswz,
                        const float* __restrict__ bias, const float* __restrict__ scale,
                        const float* __restrict__ shift, int relu,
                        float* __restrict__ Cf, int ldf,
                        ushort_t* __restrict__ Cb, int ldb, int swzout) {
    if (obase) {
        int base = *obase;
        M = *oend - base;
        A += (size_t)base * KP;
    }
    int m0 = blockIdx.x * MB, n0 = blockIdx.y * NB;
    if (m0 >= M) return;
    __shared__ ushort_t As[MB * 32];
    __shared__ ushort_t Bs[NB * 32];
    int tid = threadIdx.x;
    int lane = tid & 63, wid = tid >> 6;
    int wm = wid >> 1, wn = wid & 1;
    f32x4 acc[4][4];
    #pragma unroll
    for (int mi = 0; mi < 4; mi++)
        #pragma unroll
        for (int ni = 0; ni < 4; ni++)
            acc[mi][ni] = (f32x4){0.f, 0.f, 0.f, 0.f};

    const ushort_t* Ab = A + (size_t)m0 * KP;
    const ushort_t* Bb = BT + (size_t)n0 * KP;
    int lr = lane & 15, lg = lane >> 4;
    int amask = aswz ? 3 : 0;

    for (int k0 = 0; k0 < KP; k0 += 32) {
        #pragma unroll
        for (int i = 0; i < 2; i++) {
            int li = tid + 256 * i;
            int r = li >> 2, u = li & 3;
            gl_lds16(Ab + (size_t)r * KP + k0 + u * 8, &As[(size_t)(li & ~63) * 8]);
        }
        #pragma unroll
        for (int i = 0; i < 2; i++) {
            int li = tid + 256 * i;
            int r = li >> 2, u = li & 3;
            gl_lds16(Bb + (size_t)r * KP + k0 + u * 8, &Bs[(size_t)(li & ~63) * 8]);
        }
        __syncthreads();
        bf16x8 af[4], bv[4];
        #pragma unroll
        for (int mi = 0; mi < 4; mi++) {
            int rr = wm * 64 + mi * 16 + lr;
            int uu = lg ^ ((rr >> 1) & amask);
            af[mi] = *(const bf16x8*)&As[rr * 32 + uu * 8];
        }
        #pragma unroll
        for (int ni = 0; ni < 4; ni++) {
            int rr = wn * 64 + ni * 16 + lr;
            int uu = lg ^ ((rr >> 1) & 3);
            bv[ni] = *(const bf16x8*)&Bs[rr * 32 + uu * 8];
        }
        #pragma unroll
        for (int mi = 0; mi < 4; mi++)
            #pragma unroll
            for (int ni = 0; ni < 4; ni++)
                acc[mi][ni] = __builtin_amdgcn_mfma_f32_16x16x32_bf16(
                    af[mi], bv[ni], acc[mi][ni], 0, 0, 0);
        __syncthreads();
    }

    #pragma unroll
    for (int ni = 0; ni < 4; ni++) {
        int gn = n0 + wn * 64 + ni * 16 + lr;
        if (gn >= Nn) continue;
        float bvv = bias[gn];
        float sc = scale ? scale[gn] * BNS : 0.f;
        float sh = shift ? shift[gn] : 0.f;
        #pragma unroll
        for (int mi = 0; mi < 4; mi++) {
            #pragma unroll
            for (int t = 0; t < 4; t++) {
                int gm = m0 + wm * 64 + mi * 16 + lg * 4 + t;
                if (gm >= M) continue;
                float v = acc[mi][ni][t] + bvv;
                if (scale) v = v * sc + sh;
                if (relu) v = fmaxf(v, 0.f);
                if (Cf) Cf[(size_t)gm * ldf + gn] = v;
                else    Cb[(size_t)gm * ldb + (swzout ? swzcol(gm, gn) : gn)] = f2b(v);
            }
        }
    }
}

// ---------------- fp32 GEMM (head only) ----------------
#define GBM 128
#define GBN 64
#define GBK 16
__launch_bounds__(256)
__global__ void k_gemm(const float* __restrict__ A, const float* __restrict__ Bm,
                       float* __restrict__ C, int M, int Nn, int K,
                       const float* __restrict__ bias) {
    __shared__ float As[GBM][GBK + 1];
    __shared__ float Bs[GBK][GBN];
    int tid = threadIdx.x;
    int tx = tid & 15, ty = tid >> 4;
    int m0 = blockIdx.x * GBM, n0 = blockIdx.y * GBN;
    float acc[8][4];
    #pragma unroll
    for (int i = 0; i < 8; i++)
        #pragma unroll
        for (int j = 0; j < 4; j++) acc[i][j] = 0.f;

    for (int k0 = 0; k0 < K; k0 += GBK) {
        #pragma unroll
        for (int i = 0; i < 8; i++) {
            int li = tid + i * 256;
            int r = li >> 4, c = li & 15;
            int gm = m0 + r, gk = k0 + c;
            As[r][c] = (gm < M && gk < K) ? A[(size_t)gm * K + gk] : 0.f;
        }
        #pragma unroll
        for (int i = 0; i < 4; i++) {
            int li = tid + i * 256;
            int r = li >> 6, c = li & 63;
            int gk = k0 + r, gn = n0 + c;
            Bs[r][c] = (gk < K && gn < Nn) ? Bm[(size_t)gk * Nn + gn] : 0.f;
        }
        __syncthreads();
        #pragma unroll
        for (int k = 0; k < GBK; k++) {
            float4 b4 = *reinterpret_cast<const float4*>(&Bs[k][4 * tx]);
            #pragma unroll
            for (int i = 0; i < 8; i++) {
                float a = As[ty + 16 * i][k];
                acc[i][0] += a * b4.x;
                acc[i][1] += a * b4.y;
                acc[i][2] += a * b4.z;
                acc[i][3] += a * b4.w;
            }
        }
        __syncthreads();
    }
    #pragma unroll
    for (int i = 0; i < 8; i++) {
        int gm = m0 + ty + 16 * i;
        if (gm >= M) continue;
        #pragma unroll
        for (int j = 0; j < 4; j++) {
            int gn = n0 + 4 * tx + j;
            if (gn >= Nn) continue;
            C[(size_t)gm * Nn + gn] = acc[i][j] + bias[gn];
        }
    }
}

// ---------------- per-graph segment sums (h_bf is swizzled) ----------------
__global__ void k_vtmp(const ushort_t* __restrict__ h_bf, const float* __restrict__ vn,
                       const int* __restrict__ rs, ushort_t* __restrict__ vtmp_bf) {
    int b = blockIdx.x; int j = threadIdx.x;
    if (j >= H_) return;
    int s = rs[b], e = rs[b + 1];
    int jbase = (j & ~31) | (j & 7);
    int ju = (j >> 3) & 3;
    float acc = 0.f;
    for (int n = s; n < e; n++) {
        int col = jbase | ((ju ^ ((n >> 1) & 3)) << 3);
        acc += b2f(h_bf[(size_t)n * KP_ + col]);
    }
    vtmp_bf[(size_t)b * KP_ + swzcol(b, j)] = f2b(acc + vn[(size_t)b * H_ + j]);
}

__global__ void k_gmean(const ushort_t* __restrict__ h_bf, const int* __restrict__ rs,
                        float* __restrict__ gm) {
    int b = blockIdx.x; int j = threadIdx.x;
    if (j >= H_) return;
    int s = rs[b], e = rs[b + 1];
    int jbase = (j & ~31) | (j & 7);
    int ju = (j >> 3) & 3;
    float acc = 0.f;
    for (int n = s; n < e; n++) {
        int col = jbase | ((ju ^ ((n >> 1) & 3)) << 3);
        acc += b2f(h_bf[(size_t)n * KP_ + col]);
    }
    int cnt = e - s; if (cnt < 1) cnt = 1;
    gm[(size_t)b * H_ + j] = acc / (float)cnt;
}

// ---------------- lean edge aggregation (x linear, eproj precomputed) ------------
__global__ void k_agg(const ushort_t* __restrict__ x_bf, const ushort_t* __restrict__ eproj,
                      ushort_t* __restrict__ h_bf,
                      const int* __restrict__ off, const int* __restrict__ csrc,
                      const float* __restrict__ en_csr, int node0,
                      const float* __restrict__ invdeg,
                      const float* __restrict__ root_l, const float* __restrict__ gamma_l,
                      const float* __restrict__ beta_l,
                      const float* __restrict__ vn_next, const int* __restrict__ gid,
                      int relu) {
    int n = node0 + blockIdx.x; int j = threadIdx.x;
    if (j >= H_) return;
    int base = off[node0];
    int s = off[n], e = off[n + 1];
    const ushort_t* ep = eproj + (size_t)(s - base) * KP_ + j;
    float acc = 0.f;
    for (int idx = s; idx < e; idx++, ep += KP_) {
        int sn = csrc[idx];
        float msg = b2f(x_bf[(size_t)sn * KP_ + j]) + b2f(*ep);
        acc += en_csr[idx] * fmaxf(msg, 0.f);
    }
    float xn = b2f(x_bf[(size_t)n * KP_ + j]);
    float v = acc + fmaxf(xn + root_l[j], 0.f) * invdeg[n];
    v = v * (gamma_l[j] * BNS) + beta_l[j];
    if (relu) v = fmaxf(v, 0.f);
    if (vn_next) v += vn_next[(size_t)gid[n] * H_ + j];
    h_bf[(size_t)n * KP_ + swzcol(n, j)] = f2b(v);
}

// ---------------- launch ----------------
extern "C" void kernel_launch(void* const* d_in, const int* in_sizes, int n_in,
                              void* d_out, int out_size, void* d_ws, size_t ws_size,
                              hipStream_t stream) {
    const int* node_types = (const int*)d_in[0];
    const int* src        = (const int*)d_in[1];
    const int* dst        = (const int*)d_in[2];
    const int* graph_ids  = (const int*)d_in[3];
    const float* edge_feats = (const float*)d_in[4];
    const float* node_emb   = (const float*)d_in[5];
    const float* Wn   = (const float*)d_in[6];
    const float* bn   = (const float*)d_in[7];
    const float* We   = (const float*)d_in[8];
    const float* be   = (const float*)d_in[9];
    const float* root = (const float*)d_in[10];
    const float* gamma = (const float*)d_in[11];
    const float* beta  = (const float*)d_in[12];
    const float* vn_emb = (const float*)d_in[13];
    const float* W1  = (const float*)d_in[14];
    const float* b1  = (const float*)d_in[15];
    const float* g1  = (const float*)d_in[16];
    const float* be1 = (const float*)d_in[17];
    const float* W2  = (const float*)d_in[18];
    const float* b2  = (const float*)d_in[19];
    const float* g2  = (const float*)d_in[20];
    const float* be2 = (const float*)d_in[21];
    const float* pW  = (const float*)d_in[22];
    const float* pb  = (const float*)d_in[23];
    float* out = (float*)d_out;

    // workspace carve-up (~240 MB; R1 proved >=253 MB available)
    char* p = (char*)d_ws;
    auto alloc = [&](size_t bytes) { void* q = (void*)p; p += (bytes + 255) & ~(size_t)255; return q; };
    ushort_t* h_bf   = (ushort_t*)alloc((size_t)MPAD * KP_ * 2);        // 64 MB (swizzled)
    ushort_t* x_bf   = (ushort_t*)alloc((size_t)MPAD * KP_ * 2);        // 64 MB (linear)
    ushort_t* eproj  = (ushort_t*)alloc((size_t)(EGB_ * MB) * KP_ * 2); // 66.6 MB (linear, chunk)
    ushort_t* ef_bf  = (ushort_t*)alloc((size_t)(E_ + 128) * 32 * 2);   // 25.6 MB (linear)
    ushort_t* WnT    = (ushort_t*)alloc((size_t)L_ * 384 * KP_ * 2);
    ushort_t* WeT    = (ushort_t*)alloc((size_t)L_ * 384 * 32 * 2);
    ushort_t* W1T    = (ushort_t*)alloc((size_t)4 * 640 * KP_ * 2);
    ushort_t* W2T    = (ushort_t*)alloc((size_t)4 * 384 * 640 * 2);
    ushort_t* vtmp_bf= (ushort_t*)alloc((size_t)B_ * KP_ * 2);
    ushort_t* z_bf   = (ushort_t*)alloc((size_t)B_ * 640 * 2);
    float* vn    = (float*)alloc((size_t)B_ * H_ * 4);
    float* gmean = (float*)alloc((size_t)B_ * H_ * 4);
    float* nrm   = (float*)alloc((size_t)N_ * 4);
    float* invdeg= (float*)alloc((size_t)N_ * 4);
    int* degi    = (int*)alloc((size_t)N_ * 4);
    int* csr_off = (int*)alloc((size_t)(N_ + 1) * 4);
    int* cursor  = (int*)alloc((size_t)N_ * 4);
    int* csr_src = (int*)alloc((size_t)E_ * 4);
    float* en_csr= (float*)alloc((size_t)E_ * 4);
    int* rs      = (int*)alloc((size_t)(B_ + 1) * 4);
    int* partial = (int*)alloc((size_t)128 * 4);

    const int SCAN_NB = (N_ + 1023) / 1024;  // 98

    // degree histogram + norms
    hipMemsetAsync(degi, 0, (size_t)N_ * 4, stream);
    hipMemsetAsync(ef_bf, 0, (size_t)(E_ + 128) * 32 * 2, stream);  // K-pad + row-pad zeros
    k_hist<<<(E_ + 255) / 256, 256, 0, stream>>>(dst, degi, E_);
    k_norm<<<(N_ + 255) / 256, 256, 0, stream>>>(degi, nrm, invdeg, N_);

    // CSR offsets = exclusive scan of degi
    k_scan1<<<SCAN_NB, 1024, 0, stream>>>(degi, csr_off, partial, N_);
    k_scan2<<<1, 1, 0, stream>>>(partial, SCAN_NB, csr_off + N_);
    k_scan3<<<SCAN_NB, 1024, 0, stream>>>(csr_off, partial, N_);
    hipMemcpyAsync(cursor, csr_off, (size_t)N_ * 4, hipMemcpyDeviceToDevice, stream);
    k_scatter<<<(E_ + 255) / 256, 256, 0, stream>>>(dst, src, edge_feats, nrm,
                                                    cursor, csr_src, ef_bf, en_csr, E_);

    // graph segment boundaries (graph_ids sorted)
    k_rowstart<<<(B_ + 1 + 255) / 256, 256, 0, stream>>>(graph_ids, rs, N_, B_);

    // weights -> bf16 transposed swizzled
    k_convW<<<(L_ * 384 * (KP_ / 8) + 255) / 256, 256, 0, stream>>>(Wn, WnT, L_, H_, H_, KP_, 384);
    k_convW<<<(L_ * 384 * 4 + 255) / 256, 256, 0, stream>>>(We, WeT, L_, EF_, H_, 32, 384);
    k_convW<<<(4 * 640 * (KP_ / 8) + 255) / 256, 256, 0, stream>>>(W1, W1T, 4, H_, 2 * H_, KP_, 640);
    k_convW<<<(4 * 384 * (640 / 8) + 255) / 256, 256, 0, stream>>>(W2, W2T, 4, 2 * H_, H_, 640, 384);

    // h = node_emb[nt] + vn_emb; vn = vn_emb
    k_hinit<<<N_, 320, 0, stream>>>(node_types, node_emb, vn_emb, h_bf);
    k_vninit<<<B_, 320, 0, stream>>>(vn_emb, vn);

    dim3 gx(MPAD / MB, 3);    // x GEMM: 782 x 3
    dim3 ge(EGB_, 3);         // eproj GEMM per chunk: 813 x 3
    dim3 gz(B_ / MB, 5);      // z GEMM: 16 x 5
    dim3 gv(B_ / MB, 3);      // vn GEMM: 16 x 3
    dim3 gh((B_ + GBM - 1) / GBM, (T_ + GBN - 1) / GBN);  // head: 16 x 2

    for (int l = 0; l < L_; l++) {
        // x = h @ Wn[l] + bn[l]  -> bf16 LINEAR
        k_bgemm<<<gx, 256, 0, stream>>>(h_bf, WnT + (size_t)l * 384 * KP_,
                                        N_, H_, KP_, nullptr, nullptr, 1,
                                        bn + (size_t)l * H_, nullptr, nullptr, 0,
                                        nullptr, 0, x_bf, KP_, 0);
        if (l < L_ - 1) {
            k_vtmp<<<B_, 320, 0, stream>>>(h_bf, vn, rs, vtmp_bf);
            // z = relu(bn1(vtmp @ W1 + b1)) -> bf16 swizzled [B][640]
            k_bgemm<<<gz, 256, 0, stream>>>(vtmp_bf, W1T + (size_t)l * 640 * KP_,
                                            B_, 2 * H_, KP_, nullptr, nullptr, 1,
                                            b1 + (size_t)l * 2 * H_,
                                            g1 + (size_t)l * 2 * H_, be1 + (size_t)l * 2 * H_, 1,
                                            nullptr, 0, z_bf, 640, 1);
            // vn = relu(bn2(z @ W2 + b2)) -> fp32 [B][300]
            k_bgemm<<<gv, 256, 0, stream>>>(z_bf, W2T + (size_t)l * 384 * 640,
                                            B_, H_, 640, nullptr, nullptr, 1,
                                            b2 + (size_t)l * H_,
                                            g2 + (size_t)l * H_, be2 + (size_t)l * H_, 1,
                                            vn, H_, nullptr, 0, 0);
        }
        // chunked: eproj = bf16(ef @ We[l] + be[l]); then lean aggregation
        for (int c = 0; c < 4; c++) {
            k_bgemm<<<ge, 256, 0, stream>>>(ef_bf, WeT + (size_t)l * 384 * 32,
                                            0, H_, 32,
                                            csr_off + c * CN_, csr_off + (c + 1) * CN_, 0,
                                            be + (size_t)l * H_, nullptr, nullptr, 0,
                                            nullptr, 0, eproj, KP_, 0);
            k_agg<<<CN_, 320, 0, stream>>>(x_bf, eproj, h_bf, csr_off, csr_src,
                                           en_csr, c * CN_, invdeg,
                                           root + (size_t)l * H_,
                                           gamma + (size_t)l * H_, beta + (size_t)l * H_,
                                           (l < L_ - 1) ? vn : nullptr, graph_ids,
                                           (l < L_ - 1) ? 1 : 0);
        }
    }

    // readout: gmean (fp32) -> head (fp32)
    k_gmean<<<B_, 320, 0, stream>>>(h_bf, rs, gmean);
    k_gemm<<<gh, 256, 0, stream>>>(gmean, pW, out, B_, T_, H_, pb);
}

// Round 6
// 2100.259 us; speedup vs baseline: 1.4829x; 1.4829x over previous
//
#include <hip/hip_runtime.h>
#include <hip/hip_bf16.h>
#include <hip/hip_fp16.h>

// Problem constants (fixed by the reference)
#define N_ 100000
#define MPAD 100096          // 782 * 128
#define E_ 400000
#define B_ 2048
#define H_ 300
#define KP_ 320              // H padded to mult of 32
#define L_ 5
#define EF_ 16
#define T_ 128
#define BNS 0.9999950000374997f  // 1/sqrt(1+1e-5)

typedef unsigned short ushort_t;
typedef short bf16x8 __attribute__((ext_vector_type(8)));
typedef float f32x4 __attribute__((ext_vector_type(4)));

__device__ __forceinline__ ushort_t f2b(float v) {
    unsigned u = __float_as_uint(v);
    unsigned r = (u + 0x7FFFu + ((u >> 16) & 1u)) >> 16;
    return (ushort_t)r;
}

__device__ __forceinline__ float b2f(ushort_t u) {
    return __uint_as_float(((unsigned)u) << 16);
}

__device__ __forceinline__ void gl_lds16(const void* g, void* l) {
    __builtin_amdgcn_global_load_lds(
        (const __attribute__((address_space(1))) void*)g,
        (__attribute__((address_space(3))) void*)l, 16, 0, 0);
}

// swizzled column for logical (row r, col j) in a swizzled bf16 buffer
__device__ __forceinline__ int swzcol(int r, int j) {
    int u = ((j >> 3) & 3) ^ ((r >> 1) & 3);
    return (j & ~31) | (u << 3) | (j & 7);
}

// ---------------- CSR build ----------------
__global__ void k_hist(const int* __restrict__ dst, int* __restrict__ degi, int E) {
    int e = blockIdx.x * blockDim.x + threadIdx.x;
    if (e < E) atomicAdd(&degi[dst[e]], 1);
}

__global__ void k_norm(const int* __restrict__ degi, float* __restrict__ nrm,
                       float* __restrict__ invdeg, int N) {
    int n = blockIdx.x * blockDim.x + threadIdx.x;
    if (n < N) {
        float d = (float)degi[n] + 1.0f;
        nrm[n] = 1.0f / sqrtf(d);
        invdeg[n] = 1.0f / d;
    }
}

__global__ void k_scan1(const int* __restrict__ in, int* __restrict__ out,
                        int* __restrict__ partial, int N) {
    __shared__ int s[1024];
    int i = blockIdx.x * 1024 + threadIdx.x;
    int v = (i < N) ? in[i] : 0;
    s[threadIdx.x] = v;
    __syncthreads();
    for (int off = 1; off < 1024; off <<= 1) {
        int t = (threadIdx.x >= off) ? s[threadIdx.x - off] : 0;
        __syncthreads();
        s[threadIdx.x] += t;
        __syncthreads();
    }
    if (i < N) out[i] = s[threadIdx.x] - v;  // exclusive
    if (threadIdx.x == 1023) partial[blockIdx.x] = s[1023];
}

__global__ void k_scan2(int* __restrict__ partial, int nb, int* __restrict__ totalOut) {
    if (blockIdx.x == 0 && threadIdx.x == 0) {
        int run = 0;
        for (int i = 0; i < nb; i++) { int v = partial[i]; partial[i] = run; run += v; }
        *totalOut = run;
    }
}

__global__ void k_scan3(int* __restrict__ out, const int* __restrict__ partial, int N) {
    int i = blockIdx.x * 1024 + threadIdx.x;
    if (i < N) out[i] += partial[blockIdx.x];
}

// scatter edges into CSR order; pre-gather edge feats (f16, 32 B/edge) + per-edge norm
__global__ void k_scatter(const int* __restrict__ dst, const int* __restrict__ src,
                          const float* __restrict__ ef, const float* __restrict__ nrm,
                          int* __restrict__ cursor, int* __restrict__ csrc,
                          ushort_t* __restrict__ ef16, float* __restrict__ en_csr, int E) {
    int e = blockIdx.x * blockDim.x + threadIdx.x;
    if (e >= E) return;
    int d = dst[e], s = src[e];
    int pos = atomicAdd(&cursor[d], 1);
    csrc[pos] = s;
    en_csr[pos] = nrm[s] * nrm[d];
    const float4* ep = (const float4*)&ef[(size_t)e * EF_];
    float4 e0 = ep[0], e1 = ep[1], e2 = ep[2], e3 = ep[3];
    uint4 ua, ub;
    ua.x = __builtin_bit_cast(unsigned, __floats2half2_rn(e0.x, e0.y));
    ua.y = __builtin_bit_cast(unsigned, __floats2half2_rn(e0.z, e0.w));
    ua.z = __builtin_bit_cast(unsigned, __floats2half2_rn(e1.x, e1.y));
    ua.w = __builtin_bit_cast(unsigned, __floats2half2_rn(e1.z, e1.w));
    ub.x = __builtin_bit_cast(unsigned, __floats2half2_rn(e2.x, e2.y));
    ub.y = __builtin_bit_cast(unsigned, __floats2half2_rn(e2.z, e2.w));
    ub.z = __builtin_bit_cast(unsigned, __floats2half2_rn(e3.x, e3.y));
    ub.w = __builtin_bit_cast(unsigned, __floats2half2_rn(e3.z, e3.w));
    uint4* op = (uint4*)&ef16[(size_t)pos * 16];
    op[0] = ua; op[1] = ub;
}

__global__ void k_rowstart(const int* __restrict__ gid, int* __restrict__ rs, int N, int B) {
    int b = blockIdx.x * blockDim.x + threadIdx.x;
    if (b <= B) {
        int lo = 0, hi = N;
        while (lo < hi) { int mid = (lo + hi) >> 1; if (gid[mid] < b) lo = mid + 1; else hi = mid; }
        rs[b] = lo;
    }
}

// ---------------- init ----------------
__global__ void k_hinit(const int* __restrict__ nt, const float* __restrict__ emb,
                        const float* __restrict__ vn_emb,
                        ushort_t* __restrict__ h_bf) {
    int n = blockIdx.x; int j = threadIdx.x;
    if (j >= H_) return;
    float v = emb[(size_t)nt[n] * H_ + j] + vn_emb[j];
    h_bf[(size_t)n * KP_ + swzcol(n, j)] = f2b(v);
}

__global__ void k_vninit(const float* __restrict__ vn_emb, float* __restrict__ vn) {
    int b = blockIdx.x; int j = threadIdx.x;
    if (j >= H_) return;
    vn[(size_t)b * H_ + j] = vn_emb[j];
}

// weight conversion: WT[l][n][k] = W[l][k][n], bf16, zero-padded, row-swizzled
__global__ void k_convW(const float* __restrict__ W, ushort_t* __restrict__ WT,
                        int nl, int K, int Nout, int KPv, int NPBv) {
    int UPR = KPv / 8;
    int tot = nl * NPBv * UPR;
    int idx = blockIdx.x * 256 + threadIdx.x;
    if (idx >= tot) return;
    int l = idx / (NPBv * UPR); int r = idx % (NPBv * UPR);
    int n = r / UPR; int ku = r % UPR;
    int k0 = ku * 8;
    int swz = (ku & 3) ^ ((n >> 1) & 3);
    size_t d = ((size_t)l * NPBv + n) * KPv + (size_t)(k0 & ~31) + swz * 8;
    #pragma unroll
    for (int i = 0; i < 8; i++) {
        int k = k0 + i;
        float v = (k < K && n < Nout) ? W[((size_t)l * K + k) * Nout + n] : 0.f;
        WT[d + i] = f2b(v);
    }
}

// We -> packed half2 pairs: Weh[l][k2][j] = (We[l][2k2][j], We[l][2k2+1][j])
__global__ void k_convWeh(const float* __restrict__ We, unsigned* __restrict__ Weh) {
    int idx = blockIdx.x * 256 + threadIdx.x;
    if (idx >= L_ * 8 * H_) return;
    int l = idx / (8 * H_); int r = idx % (8 * H_);
    int k2 = r / H_; int j = r % H_;
    float a = We[((size_t)l * EF_ + 2 * k2) * H_ + j];
    float b = We[((size_t)l * EF_ + 2 * k2 + 1) * H_ + j];
    Weh[((size_t)l * 8 + k2) * H_ + j] = __builtin_bit_cast(unsigned, __floats2half2_rn(a, b));
}

// ---------------- unified bf16 MFMA GEMM ----------------
// C = epilogue(A[M,KP] @ BT[*,KP]^T + bias). A swizzled bf16.
// Output: Cf (fp32, stride ldf) or Cb (bf16, stride ldb, swizzled iff swzout).
#define MB 128
#define NB 128
__launch_bounds__(256)
__global__ void k_bgemm(const ushort_t* __restrict__ A, const ushort_t* __restrict__ BT,
                        int M, int Nn, int KP,
                        const float* __restrict__ bias, const float* __restrict__ scale,
                        const float* __restrict__ shift, int relu,
                        float* __restrict__ Cf, int ldf,
                        ushort_t* __restrict__ Cb, int ldb, int swzout) {
    __shared__ ushort_t As[MB * 32];
    __shared__ ushort_t Bs[NB * 32];
    int tid = threadIdx.x;
    int lane = tid & 63, wid = tid >> 6;
    int wm = wid >> 1, wn = wid & 1;
    int m0 = blockIdx.x * MB, n0 = blockIdx.y * NB;
    f32x4 acc[4][4];
    #pragma unroll
    for (int mi = 0; mi < 4; mi++)
        #pragma unroll
        for (int ni = 0; ni < 4; ni++)
            acc[mi][ni] = (f32x4){0.f, 0.f, 0.f, 0.f};

    const ushort_t* Ab = A + (size_t)m0 * KP;
    const ushort_t* Bb = BT + (size_t)n0 * KP;
    int lr = lane & 15, lg = lane >> 4;

    for (int k0 = 0; k0 < KP; k0 += 32) {
        #pragma unroll
        for (int i = 0; i < 2; i++) {
            int li = tid + 256 * i;
            int r = li >> 2, u = li & 3;
            gl_lds16(Ab + (size_t)r * KP + k0 + u * 8, &As[(size_t)(li & ~63) * 8]);
        }
        #pragma unroll
        for (int i = 0; i < 2; i++) {
            int li = tid + 256 * i;
            int r = li >> 2, u = li & 3;
            gl_lds16(Bb + (size_t)r * KP + k0 + u * 8, &Bs[(size_t)(li & ~63) * 8]);
        }
        __syncthreads();
        bf16x8 af[4], bv[4];
        #pragma unroll
        for (int mi = 0; mi < 4; mi++) {
            int rr = wm * 64 + mi * 16 + lr;
            int uu = lg ^ ((rr >> 1) & 3);
            af[mi] = *(const bf16x8*)&As[rr * 32 + uu * 8];
        }
        #pragma unroll
        for (int ni = 0; ni < 4; ni++) {
            int rr = wn * 64 + ni * 16 + lr;
            int uu = lg ^ ((rr >> 1) & 3);
            bv[ni] = *(const bf16x8*)&Bs[rr * 32 + uu * 8];
        }
        #pragma unroll
        for (int mi = 0; mi < 4; mi++)
            #pragma unroll
            for (int ni = 0; ni < 4; ni++)
                acc[mi][ni] = __builtin_amdgcn_mfma_f32_16x16x32_bf16(
                    af[mi], bv[ni], acc[mi][ni], 0, 0, 0);
        __syncthreads();
    }

    #pragma unroll
    for (int ni = 0; ni < 4; ni++) {
        int gn = n0 + wn * 64 + ni * 16 + lr;
        if (gn >= Nn) continue;
        float bvv = bias[gn];
        float sc = scale ? scale[gn] * BNS : 0.f;
        float sh = shift ? shift[gn] : 0.f;
        #pragma unroll
        for (int mi = 0; mi < 4; mi++) {
            #pragma unroll
            for (int t = 0; t < 4; t++) {
                int gm = m0 + wm * 64 + mi * 16 + lg * 4 + t;
                if (gm >= M) continue;
                float v = acc[mi][ni][t] + bvv;
                if (scale) v = v * sc + sh;
                if (relu) v = fmaxf(v, 0.f);
                if (Cf) Cf[(size_t)gm * ldf + gn] = v;
                else    Cb[(size_t)gm * ldb + (swzout ? swzcol(gm, gn) : gn)] = f2b(v);
            }
        }
    }
}

// ---------------- per-graph segment sum -> vtmp (swizzled bf16) ----------------
__global__ void k_vtmp(const ushort_t* __restrict__ h_bf, const float* __restrict__ vn,
                       const int* __restrict__ rs, ushort_t* __restrict__ vtmp_bf) {
    int b = blockIdx.x; int j = threadIdx.x;
    if (j >= H_) return;
    int s = rs[b], e = rs[b + 1];
    int jbase = (j & ~31) | (j & 7);
    int ju = (j >> 3) & 3;
    float acc = 0.f;
    for (int n = s; n < e; n++) {
        int col = jbase | ((ju ^ ((n >> 1) & 3)) << 3);
        acc += b2f(h_bf[(size_t)n * KP_ + col]);
    }
    vtmp_bf[(size_t)b * KP_ + swzcol(b, j)] = f2b(acc + vn[(size_t)b * H_ + j]);
}

// ---------------- fused readout: gmean (seg-sum/cnt) -> LDS -> head dot ----------------
__global__ void k_readout(const ushort_t* __restrict__ h_bf, const int* __restrict__ rs,
                          const float* __restrict__ pW, const float* __restrict__ pb,
                          float* __restrict__ out) {
    __shared__ float g[H_ + 4];
    int b = blockIdx.x; int j = threadIdx.x;
    int s = rs[b], e = rs[b + 1];
    if (j < H_) {
        int jbase = (j & ~31) | (j & 7);
        int ju = (j >> 3) & 3;
        float acc = 0.f;
        for (int n = s; n < e; n++) {
            int col = jbase | ((ju ^ ((n >> 1) & 3)) << 3);
            acc += b2f(h_bf[(size_t)n * KP_ + col]);
        }
        int cnt = e - s; if (cnt < 1) cnt = 1;
        g[j] = acc / (float)cnt;
    }
    __syncthreads();
    if (j < T_) {
        float o = pb[j];
        #pragma unroll 4
        for (int k = 0; k < H_; k++) o = fmaf(g[k], pW[(size_t)k * T_ + j], o);
        out[(size_t)b * T_ + j] = o;
    }
}

// ---------------- fused edge aggregation (f16 packed eproj on the fly) ------------
__global__ void k_agg(const ushort_t* __restrict__ x_bf,
                      ushort_t* __restrict__ h_bf,
                      const int* __restrict__ off, const int* __restrict__ csrc,
                      const ushort_t* __restrict__ ef16, const float* __restrict__ en_csr,
                      const unsigned* __restrict__ Weh_l, const float* __restrict__ be_l,
                      const float* __restrict__ invdeg,
                      const float* __restrict__ root_l, const float* __restrict__ gamma_l,
                      const float* __restrict__ beta_l,
                      const float* __restrict__ vn_next, const int* __restrict__ gid,
                      int relu) {
    int n = blockIdx.x; int j = threadIdx.x;
    if (j >= H_) return;
    __half2 wh[8];
    #pragma unroll
    for (int k2 = 0; k2 < 8; k2++)
        wh[k2] = __builtin_bit_cast(__half2, Weh_l[k2 * H_ + j]);
    int s = off[n], e = off[n + 1];
    float bej = be_l[j];
    float acc = 0.f;
    for (int idx = s; idx < e; idx++) {
        int sn = csrc[idx];
        float xv = b2f(x_bf[(size_t)sn * KP_ + j]);
        const uint4* e4 = (const uint4*)&ef16[(size_t)idx * 16];
        uint4 ea = e4[0], eb = e4[1];
        __half2 hs = __floats2half2_rn(0.f, 0.f);
        hs = __hfma2(__builtin_bit_cast(__half2, ea.x), wh[0], hs);
        hs = __hfma2(__builtin_bit_cast(__half2, ea.y), wh[1], hs);
        hs = __hfma2(__builtin_bit_cast(__half2, ea.z), wh[2], hs);
        hs = __hfma2(__builtin_bit_cast(__half2, ea.w), wh[3], hs);
        hs = __hfma2(__builtin_bit_cast(__half2, eb.x), wh[4], hs);
        hs = __hfma2(__builtin_bit_cast(__half2, eb.y), wh[5], hs);
        hs = __hfma2(__builtin_bit_cast(__half2, eb.z), wh[6], hs);
        hs = __hfma2(__builtin_bit_cast(__half2, eb.w), wh[7], hs);
        float ev = bej + __low2float(hs) + __high2float(hs);
        acc = fmaf(en_csr[idx], fmaxf(xv + ev, 0.f), acc);
    }
    float xn = b2f(x_bf[(size_t)n * KP_ + j]);
    float v = acc + fmaxf(xn + root_l[j], 0.f) * invdeg[n];
    v = v * (gamma_l[j] * BNS) + beta_l[j];
    if (relu) v = fmaxf(v, 0.f);
    if (vn_next) v += vn_next[(size_t)gid[n] * H_ + j];
    h_bf[(size_t)n * KP_ + swzcol(n, j)] = f2b(v);
}

// ---------------- launch ----------------
extern "C" void kernel_launch(void* const* d_in, const int* in_sizes, int n_in,
                              void* d_out, int out_size, void* d_ws, size_t ws_size,
                              hipStream_t stream) {
    const int* node_types = (const int*)d_in[0];
    const int* src        = (const int*)d_in[1];
    const int* dst        = (const int*)d_in[2];
    const int* graph_ids  = (const int*)d_in[3];
    const float* edge_feats = (const float*)d_in[4];
    const float* node_emb   = (const float*)d_in[5];
    const float* Wn   = (const float*)d_in[6];
    const float* bn   = (const float*)d_in[7];
    const float* We   = (const float*)d_in[8];
    const float* be   = (const float*)d_in[9];
    const float* root = (const float*)d_in[10];
    const float* gamma = (const float*)d_in[11];
    const float* beta  = (const float*)d_in[12];
    const float* vn_emb = (const float*)d_in[13];
    const float* W1  = (const float*)d_in[14];
    const float* b1  = (const float*)d_in[15];
    const float* g1  = (const float*)d_in[16];
    const float* be1 = (const float*)d_in[17];
    const float* W2  = (const float*)d_in[18];
    const float* b2  = (const float*)d_in[19];
    const float* g2  = (const float*)d_in[20];
    const float* be2 = (const float*)d_in[21];
    const float* pW  = (const float*)d_in[22];
    const float* pb  = (const float*)d_in[23];
    float* out = (float*)d_out;

    // workspace carve-up (~155 MB; R1 proved >=253 MB available)
    char* p = (char*)d_ws;
    auto alloc = [&](size_t bytes) { void* q = (void*)p; p += (bytes + 255) & ~(size_t)255; return q; };
    ushort_t* h_bf   = (ushort_t*)alloc((size_t)MPAD * KP_ * 2);        // 64 MB (swizzled)
    ushort_t* x_bf   = (ushort_t*)alloc((size_t)MPAD * KP_ * 2);        // 64 MB (linear)
    ushort_t* ef16   = (ushort_t*)alloc((size_t)E_ * 16 * 2);           // 12.8 MB (f16 CSR)
    ushort_t* WnT    = (ushort_t*)alloc((size_t)L_ * 384 * KP_ * 2);
    unsigned* Weh    = (unsigned*)alloc((size_t)L_ * 8 * H_ * 4);
    ushort_t* W1T    = (ushort_t*)alloc((size_t)4 * 640 * KP_ * 2);
    ushort_t* W2T    = (ushort_t*)alloc((size_t)4 * 384 * 640 * 2);
    ushort_t* vtmp_bf= (ushort_t*)alloc((size_t)B_ * KP_ * 2);
    ushort_t* z_bf   = (ushort_t*)alloc((size_t)B_ * 640 * 2);
    float* vn    = (float*)alloc((size_t)B_ * H_ * 4);
    float* nrm   = (float*)alloc((size_t)N_ * 4);
    float* invdeg= (float*)alloc((size_t)N_ * 4);
    int* degi    = (int*)alloc((size_t)N_ * 4);
    int* csr_off = (int*)alloc((size_t)(N_ + 1) * 4);
    int* cursor  = (int*)alloc((size_t)N_ * 4);
    int* csr_src = (int*)alloc((size_t)E_ * 4);
    float* en_csr= (float*)alloc((size_t)E_ * 4);
    int* rs      = (int*)alloc((size_t)(B_ + 1) * 4);
    int* partial = (int*)alloc((size_t)128 * 4);

    const int SCAN_NB = (N_ + 1023) / 1024;  // 98

    // degree histogram + norms
    hipMemsetAsync(degi, 0, (size_t)N_ * 4, stream);
    k_hist<<<(E_ + 255) / 256, 256, 0, stream>>>(dst, degi, E_);
    k_norm<<<(N_ + 255) / 256, 256, 0, stream>>>(degi, nrm, invdeg, N_);

    // CSR offsets = exclusive scan of degi
    k_scan1<<<SCAN_NB, 1024, 0, stream>>>(degi, csr_off, partial, N_);
    k_scan2<<<1, 1, 0, stream>>>(partial, SCAN_NB, csr_off + N_);
    k_scan3<<<SCAN_NB, 1024, 0, stream>>>(csr_off, partial, N_);
    hipMemcpyAsync(cursor, csr_off, (size_t)N_ * 4, hipMemcpyDeviceToDevice, stream);
    k_scatter<<<(E_ + 255) / 256, 256, 0, stream>>>(dst, src, edge_feats, nrm,
                                                    cursor, csr_src, ef16, en_csr, E_);

    // graph segment boundaries (graph_ids sorted)
    k_rowstart<<<(B_ + 1 + 255) / 256, 256, 0, stream>>>(graph_ids, rs, N_, B_);

    // weights -> bf16 transposed swizzled; We -> packed half2
    k_convW<<<(L_ * 384 * (KP_ / 8) + 255) / 256, 256, 0, stream>>>(Wn, WnT, L_, H_, H_, KP_, 384);
    k_convWeh<<<(L_ * 8 * H_ + 255) / 256, 256, 0, stream>>>(We, Weh);
    k_convW<<<(4 * 640 * (KP_ / 8) + 255) / 256, 256, 0, stream>>>(W1, W1T, 4, H_, 2 * H_, KP_, 640);
    k_convW<<<(4 * 384 * (640 / 8) + 255) / 256, 256, 0, stream>>>(W2, W2T, 4, 2 * H_, H_, 640, 384);

    // h = node_emb[nt] + vn_emb; vn = vn_emb
    k_hinit<<<N_, 320, 0, stream>>>(node_types, node_emb, vn_emb, h_bf);
    k_vninit<<<B_, 320, 0, stream>>>(vn_emb, vn);

    dim3 gx(MPAD / MB, 3);    // x GEMM: 782 x 3
    dim3 gz(B_ / MB, 5);      // z GEMM: 16 x 5
    dim3 gv(B_ / MB, 3);      // vn GEMM: 16 x 3

    for (int l = 0; l < L_; l++) {
        // x = h @ Wn[l] + bn[l]  -> bf16 LINEAR
        k_bgemm<<<gx, 256, 0, stream>>>(h_bf, WnT + (size_t)l * 384 * KP_,
                                        N_, H_, KP_,
                                        bn + (size_t)l * H_, nullptr, nullptr, 0,
                                        nullptr, 0, x_bf, KP_, 0);
        if (l < L_ - 1) {
            k_vtmp<<<B_, 320, 0, stream>>>(h_bf, vn, rs, vtmp_bf);
            // z = relu(bn1(vtmp @ W1 + b1)) -> bf16 swizzled [B][640]
            k_bgemm<<<gz, 256, 0, stream>>>(vtmp_bf, W1T + (size_t)l * 640 * KP_,
                                            B_, 2 * H_, KP_,
                                            b1 + (size_t)l * 2 * H_,
                                            g1 + (size_t)l * 2 * H_, be1 + (size_t)l * 2 * H_, 1,
                                            nullptr, 0, z_bf, 640, 1);
            // vn = relu(bn2(z @ W2 + b2)) -> fp32 [B][300]
            k_bgemm<<<gv, 256, 0, stream>>>(z_bf, W2T + (size_t)l * 384 * 640,
                                            B_, H_, 640,
                                            b2 + (size_t)l * H_,
                                            g2 + (size_t)l * H_, be2 + (size_t)l * H_, 1,
                                            vn, H_, nullptr, 0, 0);
        }
        // h = bn(agg + relu(x+root)*invdeg) (+relu/+vn_next if l<L-1)
        k_agg<<<N_, 320, 0, stream>>>(x_bf, h_bf, csr_off, csr_src,
                                      ef16, en_csr,
                                      Weh + (size_t)l * 8 * H_, be + (size_t)l * H_,
                                      invdeg,
                                      root + (size_t)l * H_,
                                      gamma + (size_t)l * H_, beta + (size_t)l * H_,
                                      (l < L_ - 1) ? vn : nullptr, graph_ids,
                                      (l < L_ - 1) ? 1 : 0);
    }

    // fused readout: gmean -> head
    k_readout<<<B_, 320, 0, stream>>>(h_bf, rs, pW, pb, out);
}

// Round 7
// 2032.959 us; speedup vs baseline: 1.5320x; 1.0331x over previous
//
#include <hip/hip_runtime.h>
#include <hip/hip_bf16.h>
#include <hip/hip_fp16.h>

// Problem constants (fixed by the reference)
#define N_ 100000
#define MPAD 100096          // 782 * 128
#define E_ 400000
#define B_ 2048
#define H_ 300
#define KP_ 320              // H padded to mult of 32
#define L_ 5
#define EF_ 16
#define T_ 128
#define BNS 0.9999950000374997f  // 1/sqrt(1+1e-5)

typedef unsigned short ushort_t;
typedef short bf16x8 __attribute__((ext_vector_type(8)));
typedef float f32x4 __attribute__((ext_vector_type(4)));

__device__ __forceinline__ ushort_t f2b(float v) {
    unsigned u = __float_as_uint(v);
    unsigned r = (u + 0x7FFFu + ((u >> 16) & 1u)) >> 16;
    return (ushort_t)r;
}

__device__ __forceinline__ float b2f(ushort_t u) {
    return __uint_as_float(((unsigned)u) << 16);
}

__device__ __forceinline__ void gl_lds16(const void* g, void* l) {
    __builtin_amdgcn_global_load_lds(
        (const __attribute__((address_space(1))) void*)g,
        (__attribute__((address_space(3))) void*)l, 16, 0, 0);
}

// swizzled column for logical (row r, col j) in a swizzled bf16 buffer
__device__ __forceinline__ int swzcol(int r, int j) {
    int u = ((j >> 3) & 3) ^ ((r >> 1) & 3);
    return (j & ~31) | (u << 3) | (j & 7);
}

// ---------------- CSR build ----------------
__global__ void k_hist(const int* __restrict__ dst, int* __restrict__ degi, int E) {
    int e = blockIdx.x * blockDim.x + threadIdx.x;
    if (e < E) atomicAdd(&degi[dst[e]], 1);
}

__global__ void k_norm(const int* __restrict__ degi, float* __restrict__ nrm,
                       float* __restrict__ invdeg, int N) {
    int n = blockIdx.x * blockDim.x + threadIdx.x;
    if (n < N) {
        float d = (float)degi[n] + 1.0f;
        nrm[n] = 1.0f / sqrtf(d);
        invdeg[n] = 1.0f / d;
    }
}

__global__ void k_scan1(const int* __restrict__ in, int* __restrict__ out,
                        int* __restrict__ partial, int N) {
    __shared__ int s[1024];
    int i = blockIdx.x * 1024 + threadIdx.x;
    int v = (i < N) ? in[i] : 0;
    s[threadIdx.x] = v;
    __syncthreads();
    for (int off = 1; off < 1024; off <<= 1) {
        int t = (threadIdx.x >= off) ? s[threadIdx.x - off] : 0;
        __syncthreads();
        s[threadIdx.x] += t;
        __syncthreads();
    }
    if (i < N) out[i] = s[threadIdx.x] - v;  // exclusive
    if (threadIdx.x == 1023) partial[blockIdx.x] = s[1023];
}

// parallel scan of <=128 partials (one block of 128 threads)
__global__ void k_scan2(int* __restrict__ partial, int nb, int* __restrict__ totalOut) {
    __shared__ int sh[128];
    int t = threadIdx.x;
    int v = (t < nb) ? partial[t] : 0;
    sh[t] = v;
    __syncthreads();
    for (int off = 1; off < 128; off <<= 1) {
        int u = (t >= off) ? sh[t - off] : 0;
        __syncthreads();
        sh[t] += u;
        __syncthreads();
    }
    if (t < nb) partial[t] = sh[t] - v;  // exclusive
    if (t == 127) *totalOut = sh[127];
}

__global__ void k_scan3(int* __restrict__ out, const int* __restrict__ partial, int N) {
    int i = blockIdx.x * 1024 + threadIdx.x;
    if (i < N) out[i] += partial[blockIdx.x];
}

// scatter edges into CSR order; pre-gather edge feats (f16, 32 B/edge) + per-edge norm
__global__ void k_scatter(const int* __restrict__ dst, const int* __restrict__ src,
                          const float* __restrict__ ef, const float* __restrict__ nrm,
                          int* __restrict__ cursor, int* __restrict__ csrc,
                          ushort_t* __restrict__ ef16, float* __restrict__ en_csr, int E) {
    int e = blockIdx.x * blockDim.x + threadIdx.x;
    if (e >= E) return;
    int d = dst[e], s = src[e];
    int pos = atomicAdd(&cursor[d], 1);
    csrc[pos] = s;
    en_csr[pos] = nrm[s] * nrm[d];
    const float4* ep = (const float4*)&ef[(size_t)e * EF_];
    float4 e0 = ep[0], e1 = ep[1], e2 = ep[2], e3 = ep[3];
    uint4 ua, ub;
    ua.x = __builtin_bit_cast(unsigned, __floats2half2_rn(e0.x, e0.y));
    ua.y = __builtin_bit_cast(unsigned, __floats2half2_rn(e0.z, e0.w));
    ua.z = __builtin_bit_cast(unsigned, __floats2half2_rn(e1.x, e1.y));
    ua.w = __builtin_bit_cast(unsigned, __floats2half2_rn(e1.z, e1.w));
    ub.x = __builtin_bit_cast(unsigned, __floats2half2_rn(e2.x, e2.y));
    ub.y = __builtin_bit_cast(unsigned, __floats2half2_rn(e2.z, e2.w));
    ub.z = __builtin_bit_cast(unsigned, __floats2half2_rn(e3.x, e3.y));
    ub.w = __builtin_bit_cast(unsigned, __floats2half2_rn(e3.z, e3.w));
    uint4* op = (uint4*)&ef16[(size_t)pos * 16];
    op[0] = ua; op[1] = ub;
}

__global__ void k_rowstart(const int* __restrict__ gid, int* __restrict__ rs, int N, int B) {
    int b = blockIdx.x * blockDim.x + threadIdx.x;
    if (b <= B) {
        int lo = 0, hi = N;
        while (lo < hi) { int mid = (lo + hi) >> 1; if (gid[mid] < b) lo = mid + 1; else hi = mid; }
        rs[b] = lo;
    }
}

// ---------------- init ----------------
__global__ void k_hinit(const int* __restrict__ nt, const float* __restrict__ emb,
                        const float* __restrict__ vn_emb,
                        ushort_t* __restrict__ h_bf) {
    int n = blockIdx.x; int j = threadIdx.x;
    if (j >= H_) return;
    float v = emb[(size_t)nt[n] * H_ + j] + vn_emb[j];
    h_bf[(size_t)n * KP_ + swzcol(n, j)] = f2b(v);
}

__global__ void k_vninit(const float* __restrict__ vn_emb, float* __restrict__ vn) {
    int b = blockIdx.x; int j = threadIdx.x;
    if (j >= H_) return;
    vn[(size_t)b * H_ + j] = vn_emb[j];
}

// weight conversion: WT[l][n][k] = W[l][k][n], bf16, zero-padded, row-swizzled
__global__ void k_convW(const float* __restrict__ W, ushort_t* __restrict__ WT,
                        int nl, int K, int Nout, int KPv, int NPBv) {
    int UPR = KPv / 8;
    int tot = nl * NPBv * UPR;
    int idx = blockIdx.x * 256 + threadIdx.x;
    if (idx >= tot) return;
    int l = idx / (NPBv * UPR); int r = idx % (NPBv * UPR);
    int n = r / UPR; int ku = r % UPR;
    int k0 = ku * 8;
    int swz = (ku & 3) ^ ((n >> 1) & 3);
    size_t d = ((size_t)l * NPBv + n) * KPv + (size_t)(k0 & ~31) + swz * 8;
    #pragma unroll
    for (int i = 0; i < 8; i++) {
        int k = k0 + i;
        float v = (k < K && n < Nout) ? W[((size_t)l * K + k) * Nout + n] : 0.f;
        WT[d + i] = f2b(v);
    }
}

// We -> packed half2 pairs: Weh[l][k2][j] = (We[l][2k2][j], We[l][2k2+1][j])
__global__ void k_convWeh(const float* __restrict__ We, unsigned* __restrict__ Weh) {
    int idx = blockIdx.x * 256 + threadIdx.x;
    if (idx >= L_ * 8 * H_) return;
    int l = idx / (8 * H_); int r = idx % (8 * H_);
    int k2 = r / H_; int j = r % H_;
    float a = We[((size_t)l * EF_ + 2 * k2) * H_ + j];
    float b = We[((size_t)l * EF_ + 2 * k2 + 1) * H_ + j];
    Weh[((size_t)l * 8 + k2) * H_ + j] = __builtin_bit_cast(unsigned, __floats2half2_rn(a, b));
}

// ---------------- unified bf16 MFMA GEMM ----------------
// C = epilogue(A[M,KP] @ BT[*,KP]^T + bias). A swizzled bf16.
// Output: Cf (fp32, stride ldf) or Cb (bf16, stride ldb, swizzled iff swzout).
#define MB 128
#define NB 128
__launch_bounds__(256)
__global__ void k_bgemm(const ushort_t* __restrict__ A, const ushort_t* __restrict__ BT,
                        int M, int Nn, int KP,
                        const float* __restrict__ bias, const float* __restrict__ scale,
                        const float* __restrict__ shift, int relu,
                        float* __restrict__ Cf, int ldf,
                        ushort_t* __restrict__ Cb, int ldb, int swzout) {
    __shared__ ushort_t As[MB * 32];
    __shared__ ushort_t Bs[NB * 32];
    int tid = threadIdx.x;
    int lane = tid & 63, wid = tid >> 6;
    int wm = wid >> 1, wn = wid & 1;
    int m0 = blockIdx.x * MB, n0 = blockIdx.y * NB;
    f32x4 acc[4][4];
    #pragma unroll
    for (int mi = 0; mi < 4; mi++)
        #pragma unroll
        for (int ni = 0; ni < 4; ni++)
            acc[mi][ni] = (f32x4){0.f, 0.f, 0.f, 0.f};

    const ushort_t* Ab = A + (size_t)m0 * KP;
    const ushort_t* Bb = BT + (size_t)n0 * KP;
    int lr = lane & 15, lg = lane >> 4;

    for (int k0 = 0; k0 < KP; k0 += 32) {
        #pragma unroll
        for (int i = 0; i < 2; i++) {
            int li = tid + 256 * i;
            int r = li >> 2, u = li & 3;
            gl_lds16(Ab + (size_t)r * KP + k0 + u * 8, &As[(size_t)(li & ~63) * 8]);
        }
        #pragma unroll
        for (int i = 0; i < 2; i++) {
            int li = tid + 256 * i;
            int r = li >> 2, u = li & 3;
            gl_lds16(Bb + (size_t)r * KP + k0 + u * 8, &Bs[(size_t)(li & ~63) * 8]);
        }
        __syncthreads();
        bf16x8 af[4], bv[4];
        #pragma unroll
        for (int mi = 0; mi < 4; mi++) {
            int rr = wm * 64 + mi * 16 + lr;
            int uu = lg ^ ((rr >> 1) & 3);
            af[mi] = *(const bf16x8*)&As[rr * 32 + uu * 8];
        }
        #pragma unroll
        for (int ni = 0; ni < 4; ni++) {
            int rr = wn * 64 + ni * 16 + lr;
            int uu = lg ^ ((rr >> 1) & 3);
            bv[ni] = *(const bf16x8*)&Bs[rr * 32 + uu * 8];
        }
        #pragma unroll
        for (int mi = 0; mi < 4; mi++)
            #pragma unroll
            for (int ni = 0; ni < 4; ni++)
                acc[mi][ni] = __builtin_amdgcn_mfma_f32_16x16x32_bf16(
                    af[mi], bv[ni], acc[mi][ni], 0, 0, 0);
        __syncthreads();
    }

    #pragma unroll
    for (int ni = 0; ni < 4; ni++) {
        int gn = n0 + wn * 64 + ni * 16 + lr;
        if (gn >= Nn) continue;
        float bvv = bias[gn];
        float sc = scale ? scale[gn] * BNS : 0.f;
        float sh = shift ? shift[gn] : 0.f;
        #pragma unroll
        for (int mi = 0; mi < 4; mi++) {
            #pragma unroll
            for (int t = 0; t < 4; t++) {
                int gm = m0 + wm * 64 + mi * 16 + lg * 4 + t;
                if (gm >= M) continue;
                float v = acc[mi][ni][t] + bvv;
                if (scale) v = v * sc + sh;
                if (relu) v = fmaxf(v, 0.f);
                if (Cf) Cf[(size_t)gm * ldf + gn] = v;
                else    Cb[(size_t)gm * ldb + (swzout ? swzcol(gm, gn) : gn)] = f2b(v);
            }
        }
    }
}

// ---------------- per-graph segment sum -> vtmp (swizzled bf16) ----------------
__global__ void k_vtmp(const ushort_t* __restrict__ h_bf, const float* __restrict__ vn,
                       const int* __restrict__ rs, ushort_t* __restrict__ vtmp_bf) {
    int b = blockIdx.x; int j = threadIdx.x;
    if (j >= H_) return;
    int s = rs[b], e = rs[b + 1];
    int jbase = (j & ~31) | (j & 7);
    int ju = (j >> 3) & 3;
    float acc = 0.f;
    for (int n = s; n < e; n++) {
        int col = jbase | ((ju ^ ((n >> 1) & 3)) << 3);
        acc += b2f(h_bf[(size_t)n * KP_ + col]);
    }
    vtmp_bf[(size_t)b * KP_ + swzcol(b, j)] = f2b(acc + vn[(size_t)b * H_ + j]);
}

// ---------------- fused readout: gmean (seg-sum/cnt) -> LDS -> head dot ----------------
__global__ void k_readout(const ushort_t* __restrict__ h_bf, const int* __restrict__ rs,
                          const float* __restrict__ pW, const float* __restrict__ pb,
                          float* __restrict__ out) {
    __shared__ float g[H_ + 4];
    int b = blockIdx.x; int j = threadIdx.x;
    int s = rs[b], e = rs[b + 1];
    if (j < H_) {
        int jbase = (j & ~31) | (j & 7);
        int ju = (j >> 3) & 3;
        float acc = 0.f;
        for (int n = s; n < e; n++) {
            int col = jbase | ((ju ^ ((n >> 1) & 3)) << 3);
            acc += b2f(h_bf[(size_t)n * KP_ + col]);
        }
        int cnt = e - s; if (cnt < 1) cnt = 1;
        g[j] = acc / (float)cnt;
    }
    __syncthreads();
    if (j < T_) {
        float o = pb[j];
        #pragma unroll 4
        for (int k = 0; k < H_; k++) o = fmaf(g[k], pW[(size_t)k * T_ + j], o);
        out[(size_t)b * T_ + j] = o;
    }
}

// ---------------- fused edge aggregation, 4-way ILP over edges ------------
__device__ __forceinline__ float eproj8(const uint4& ea, const uint4& eb,
                                        const __half2* wh, float bej) {
    __half2 hs = __floats2half2_rn(0.f, 0.f);
    hs = __hfma2(__builtin_bit_cast(__half2, ea.x), wh[0], hs);
    hs = __hfma2(__builtin_bit_cast(__half2, ea.y), wh[1], hs);
    hs = __hfma2(__builtin_bit_cast(__half2, ea.z), wh[2], hs);
    hs = __hfma2(__builtin_bit_cast(__half2, ea.w), wh[3], hs);
    hs = __hfma2(__builtin_bit_cast(__half2, eb.x), wh[4], hs);
    hs = __hfma2(__builtin_bit_cast(__half2, eb.y), wh[5], hs);
    hs = __hfma2(__builtin_bit_cast(__half2, eb.z), wh[6], hs);
    hs = __hfma2(__builtin_bit_cast(__half2, eb.w), wh[7], hs);
    return bej + __low2float(hs) + __high2float(hs);
}

__global__ void k_agg(const ushort_t* __restrict__ x_bf,
                      ushort_t* __restrict__ h_bf,
                      const int* __restrict__ off, const int* __restrict__ csrc,
                      const ushort_t* __restrict__ ef16, const float* __restrict__ en_csr,
                      const unsigned* __restrict__ Weh_l, const float* __restrict__ be_l,
                      const float* __restrict__ invdeg,
                      const float* __restrict__ root_l, const float* __restrict__ gamma_l,
                      const float* __restrict__ beta_l,
                      const float* __restrict__ vn_next, const int* __restrict__ gid,
                      int relu) {
    int n = blockIdx.x; int j = threadIdx.x;
    if (j >= H_) return;
    __half2 wh[8];
    #pragma unroll
    for (int k2 = 0; k2 < 8; k2++)
        wh[k2] = __builtin_bit_cast(__half2, Weh_l[k2 * H_ + j]);
    int s = off[n], e = off[n + 1];
    float bej = be_l[j];
    float acc = 0.f;
    // 4 edges per iteration with clamped indices; en=0 neutralizes inactive slots.
    for (int base = s; base < e; base += 4) {
        int i1 = (base + 1 < e) ? base + 1 : e - 1;
        int i2 = (base + 2 < e) ? base + 2 : e - 1;
        int i3 = (base + 3 < e) ? base + 3 : e - 1;
        int sn0 = csrc[base], sn1 = csrc[i1], sn2 = csrc[i2], sn3 = csrc[i3];
        float en0 = en_csr[base];
        float en1 = (base + 1 < e) ? en_csr[i1] : 0.f;
        float en2 = (base + 2 < e) ? en_csr[i2] : 0.f;
        float en3 = (base + 3 < e) ? en_csr[i3] : 0.f;
        float xv0 = b2f(x_bf[(size_t)sn0 * KP_ + j]);
        float xv1 = b2f(x_bf[(size_t)sn1 * KP_ + j]);
        float xv2 = b2f(x_bf[(size_t)sn2 * KP_ + j]);
        float xv3 = b2f(x_bf[(size_t)sn3 * KP_ + j]);
        const uint4* p0 = (const uint4*)&ef16[(size_t)base * 16];
        const uint4* p1 = (const uint4*)&ef16[(size_t)i1 * 16];
        const uint4* p2 = (const uint4*)&ef16[(size_t)i2 * 16];
        const uint4* p3 = (const uint4*)&ef16[(size_t)i3 * 16];
        uint4 a0 = p0[0], b0 = p0[1];
        uint4 a1 = p1[0], b1 = p1[1];
        uint4 a2 = p2[0], b2 = p2[1];
        uint4 a3 = p3[0], b3 = p3[1];
        float ev0 = eproj8(a0, b0, wh, bej);
        float ev1 = eproj8(a1, b1, wh, bej);
        float ev2 = eproj8(a2, b2, wh, bej);
        float ev3 = eproj8(a3, b3, wh, bej);
        acc = fmaf(en0, fmaxf(xv0 + ev0, 0.f), acc);
        acc = fmaf(en1, fmaxf(xv1 + ev1, 0.f), acc);
        acc = fmaf(en2, fmaxf(xv2 + ev2, 0.f), acc);
        acc = fmaf(en3, fmaxf(xv3 + ev3, 0.f), acc);
    }
    float xn = b2f(x_bf[(size_t)n * KP_ + j]);
    float v = acc + fmaxf(xn + root_l[j], 0.f) * invdeg[n];
    v = v * (gamma_l[j] * BNS) + beta_l[j];
    if (relu) v = fmaxf(v, 0.f);
    if (vn_next) v += vn_next[(size_t)gid[n] * H_ + j];
    h_bf[(size_t)n * KP_ + swzcol(n, j)] = f2b(v);
}

// ---------------- launch ----------------
extern "C" void kernel_launch(void* const* d_in, const int* in_sizes, int n_in,
                              void* d_out, int out_size, void* d_ws, size_t ws_size,
                              hipStream_t stream) {
    const int* node_types = (const int*)d_in[0];
    const int* src        = (const int*)d_in[1];
    const int* dst        = (const int*)d_in[2];
    const int* graph_ids  = (const int*)d_in[3];
    const float* edge_feats = (const float*)d_in[4];
    const float* node_emb   = (const float*)d_in[5];
    const float* Wn   = (const float*)d_in[6];
    const float* bn   = (const float*)d_in[7];
    const float* We   = (const float*)d_in[8];
    const float* be   = (const float*)d_in[9];
    const float* root = (const float*)d_in[10];
    const float* gamma = (const float*)d_in[11];
    const float* beta  = (const float*)d_in[12];
    const float* vn_emb = (const float*)d_in[13];
    const float* W1  = (const float*)d_in[14];
    const float* b1  = (const float*)d_in[15];
    const float* g1  = (const float*)d_in[16];
    const float* be1 = (const float*)d_in[17];
    const float* W2  = (const float*)d_in[18];
    const float* b2  = (const float*)d_in[19];
    const float* g2  = (const float*)d_in[20];
    const float* be2 = (const float*)d_in[21];
    const float* pW  = (const float*)d_in[22];
    const float* pb  = (const float*)d_in[23];
    float* out = (float*)d_out;

    // workspace carve-up (~155 MB; R1 proved >=253 MB available)
    char* p = (char*)d_ws;
    auto alloc = [&](size_t bytes) { void* q = (void*)p; p += (bytes + 255) & ~(size_t)255; return q; };
    ushort_t* h_bf   = (ushort_t*)alloc((size_t)MPAD * KP_ * 2);        // 64 MB (swizzled)
    ushort_t* x_bf   = (ushort_t*)alloc((size_t)MPAD * KP_ * 2);        // 64 MB (linear)
    ushort_t* ef16   = (ushort_t*)alloc((size_t)E_ * 16 * 2);           // 12.8 MB (f16 CSR)
    ushort_t* WnT    = (ushort_t*)alloc((size_t)L_ * 384 * KP_ * 2);
    unsigned* Weh    = (unsigned*)alloc((size_t)L_ * 8 * H_ * 4);
    ushort_t* W1T    = (ushort_t*)alloc((size_t)4 * 640 * KP_ * 2);
    ushort_t* W2T    = (ushort_t*)alloc((size_t)4 * 384 * 640 * 2);
    ushort_t* vtmp_bf= (ushort_t*)alloc((size_t)B_ * KP_ * 2);
    ushort_t* z_bf   = (ushort_t*)alloc((size_t)B_ * 640 * 2);
    float* vn    = (float*)alloc((size_t)B_ * H_ * 4);
    float* nrm   = (float*)alloc((size_t)N_ * 4);
    float* invdeg= (float*)alloc((size_t)N_ * 4);
    int* degi    = (int*)alloc((size_t)N_ * 4);
    int* csr_off = (int*)alloc((size_t)(N_ + 1) * 4);
    int* cursor  = (int*)alloc((size_t)N_ * 4);
    int* csr_src = (int*)alloc((size_t)E_ * 4);
    float* en_csr= (float*)alloc((size_t)E_ * 4);
    int* rs      = (int*)alloc((size_t)(B_ + 1) * 4);
    int* partial = (int*)alloc((size_t)128 * 4);

    const int SCAN_NB = (N_ + 1023) / 1024;  // 98

    // degree histogram + norms
    hipMemsetAsync(degi, 0, (size_t)N_ * 4, stream);
    k_hist<<<(E_ + 255) / 256, 256, 0, stream>>>(dst, degi, E_);
    k_norm<<<(N_ + 255) / 256, 256, 0, stream>>>(degi, nrm, invdeg, N_);

    // CSR offsets = exclusive scan of degi
    k_scan1<<<SCAN_NB, 1024, 0, stream>>>(degi, csr_off, partial, N_);
    k_scan2<<<1, 128, 0, stream>>>(partial, SCAN_NB, csr_off + N_);
    k_scan3<<<SCAN_NB, 1024, 0, stream>>>(csr_off, partial, N_);
    hipMemcpyAsync(cursor, csr_off, (size_t)N_ * 4, hipMemcpyDeviceToDevice, stream);
    k_scatter<<<(E_ + 255) / 256, 256, 0, stream>>>(dst, src, edge_feats, nrm,
                                                    cursor, csr_src, ef16, en_csr, E_);

    // graph segment boundaries (graph_ids sorted)
    k_rowstart<<<(B_ + 1 + 255) / 256, 256, 0, stream>>>(graph_ids, rs, N_, B_);

    // weights -> bf16 transposed swizzled; We -> packed half2
    k_convW<<<(L_ * 384 * (KP_ / 8) + 255) / 256, 256, 0, stream>>>(Wn, WnT, L_, H_, H_, KP_, 384);
    k_convWeh<<<(L_ * 8 * H_ + 255) / 256, 256, 0, stream>>>(We, Weh);
    k_convW<<<(4 * 640 * (KP_ / 8) + 255) / 256, 256, 0, stream>>>(W1, W1T, 4, H_, 2 * H_, KP_, 640);
    k_convW<<<(4 * 384 * (640 / 8) + 255) / 256, 256, 0, stream>>>(W2, W2T, 4, 2 * H_, H_, 640, 384);

    // h = node_emb[nt] + vn_emb; vn = vn_emb
    k_hinit<<<N_, 320, 0, stream>>>(node_types, node_emb, vn_emb, h_bf);
    k_vninit<<<B_, 320, 0, stream>>>(vn_emb, vn);

    dim3 gx(MPAD / MB, 3);    // x GEMM: 782 x 3
    dim3 gz(B_ / MB, 5);      // z GEMM: 16 x 5
    dim3 gv(B_ / MB, 3);      // vn GEMM: 16 x 3

    for (int l = 0; l < L_; l++) {
        // x = h @ Wn[l] + bn[l]  -> bf16 LINEAR
        k_bgemm<<<gx, 256, 0, stream>>>(h_bf, WnT + (size_t)l * 384 * KP_,
                                        N_, H_, KP_,
                                        bn + (size_t)l * H_, nullptr, nullptr, 0,
                                        nullptr, 0, x_bf, KP_, 0);
        if (l < L_ - 1) {
            k_vtmp<<<B_, 320, 0, stream>>>(h_bf, vn, rs, vtmp_bf);
            // z = relu(bn1(vtmp @ W1 + b1)) -> bf16 swizzled [B][640]
            k_bgemm<<<gz, 256, 0, stream>>>(vtmp_bf, W1T + (size_t)l * 640 * KP_,
                                            B_, 2 * H_, KP_,
                                            b1 + (size_t)l * 2 * H_,
                                            g1 + (size_t)l * 2 * H_, be1 + (size_t)l * 2 * H_, 1,
                                            nullptr, 0, z_bf, 640, 1);
            // vn = relu(bn2(z @ W2 + b2)) -> fp32 [B][300]
            k_bgemm<<<gv, 256, 0, stream>>>(z_bf, W2T + (size_t)l * 384 * 640,
                                            B_, H_, 640,
                                            b2 + (size_t)l * H_,
                                            g2 + (size_t)l * H_, be2 + (size_t)l * H_, 1,
                                            vn, H_, nullptr, 0, 0);
        }
        // h = bn(agg + relu(x+root)*invdeg) (+relu/+vn_next if l<L-1)
        k_agg<<<N_, 320, 0, stream>>>(x_bf, h_bf, csr_off, csr_src,
                                      ef16, en_csr,
                                      Weh + (size_t)l * 8 * H_, be + (size_t)l * H_,
                                      invdeg,
                                      root + (size_t)l * H_,
                                      gamma + (size_t)l * H_, beta + (size_t)l * H_,
                                      (l < L_ - 1) ? vn : nullptr, graph_ids,
                                      (l < L_ - 1) ? 1 : 0);
    }

    // fused readout: gmean -> head
    k_readout<<<B_, 320, 0, stream>>>(h_bf, rs, pW, pb, out);
}